// Round 1
// baseline (294.767 us; speedup 1.0000x reference)
//
#include <hip/hip_runtime.h>

// Edge softmax (DGL-style) for node-flow graphs.
//   scores[e,h]    = exp(logits[e,h] - max_{e': dst[e']==dst[e]} logits[e',h])
//   norm[n,h]      = sum_{e: dst[e]==n} scores[e,h]
//
// Pass 1: scatter-max via atomicMax on an order-preserving uint32 encoding.
// Pass 2: gather max, exp, store score, atomicAdd into normalizer.
// Workspace: N*H uint32 (3.2 MB) for encoded maxima, memset to 0 (== -inf).

__device__ __forceinline__ unsigned enc_f32(float f) {
    unsigned u = __float_as_uint(f);
    // monotone map: float order -> unsigned order
    return (u & 0x80000000u) ? ~u : (u | 0x80000000u);
}
__device__ __forceinline__ float dec_f32(unsigned u) {
    return __uint_as_float((u & 0x80000000u) ? (u & 0x7FFFFFFFu) : ~u);
}

template <int H>
__global__ void smax_k(const float* __restrict__ logits,
                       const int* __restrict__ dst,
                       unsigned* __restrict__ menc, int EH) {
    int i = blockIdx.x * blockDim.x + threadIdx.x;
    if (i >= EH) return;
    int e = i / H;                 // H is a power-of-2 template constant -> shift
    int h = i - e * H;
    int d = dst[e];
    atomicMax(menc + d * H + h, enc_f32(logits[i]));
}

__global__ void smax_g(const float* __restrict__ logits,
                       const int* __restrict__ dst,
                       unsigned* __restrict__ menc, int EH, int H) {
    int i = blockIdx.x * blockDim.x + threadIdx.x;
    if (i >= EH) return;
    int e = i / H;
    int h = i - e * H;
    int d = dst[e];
    atomicMax(menc + d * H + h, enc_f32(logits[i]));
}

template <int H>
__global__ void score_k(const float* __restrict__ logits,
                        const int* __restrict__ dst,
                        const unsigned* __restrict__ menc,
                        float* __restrict__ scores,
                        float* __restrict__ norm, int EH) {
    int i = blockIdx.x * blockDim.x + threadIdx.x;
    if (i >= EH) return;
    int e = i / H;
    int h = i - e * H;
    int d = dst[e];
    float m = dec_f32(menc[d * H + h]);
    float s = expf(logits[i] - m);
    scores[i] = s;
    atomicAdd(norm + d * H + h, s);
}

__global__ void score_g(const float* __restrict__ logits,
                        const int* __restrict__ dst,
                        const unsigned* __restrict__ menc,
                        float* __restrict__ scores,
                        float* __restrict__ norm, int EH, int H) {
    int i = blockIdx.x * blockDim.x + threadIdx.x;
    if (i >= EH) return;
    int e = i / H;
    int h = i - e * H;
    int d = dst[e];
    float m = dec_f32(menc[d * H + h]);
    float s = expf(logits[i] - m);
    scores[i] = s;
    atomicAdd(norm + d * H + h, s);
}

extern "C" void kernel_launch(void* const* d_in, const int* in_sizes, int n_in,
                              void* d_out, int out_size, void* d_ws, size_t ws_size,
                              hipStream_t stream) {
    const float* logits = (const float*)d_in[0];   // [E, H, 1] f32
    const int*   dst    = (const int*)d_in[1];     // [E] i32
    // d_in[2] = num_nodes (scalar) -- N derived from out_size instead.

    const int EH = in_sizes[0];            // E*H
    const int E  = in_sizes[1];            // E
    const int H  = EH / E;                 // 8
    const int NH = out_size - EH;          // N*H

    float* scores = (float*)d_out;         // [E,H]
    float* norm   = scores + EH;           // [N,H]
    unsigned* menc = (unsigned*)d_ws;      // [N,H] encoded maxima

    // encoded 0 == -inf identity for unsigned max; norm identity is 0.
    hipMemsetAsync(menc, 0, (size_t)NH * sizeof(unsigned), stream);
    hipMemsetAsync(norm, 0, (size_t)NH * sizeof(float), stream);

    const int block = 256;
    const int grid  = (EH + block - 1) / block;

    if (H == 8) {
        smax_k<8><<<grid, block, 0, stream>>>(logits, dst, menc, EH);
        score_k<8><<<grid, block, 0, stream>>>(logits, dst, menc, scores, norm, EH);
    } else {
        smax_g<<<grid, block, 0, stream>>>(logits, dst, menc, EH, H);
        score_g<<<grid, block, 0, stream>>>(logits, dst, menc, scores, norm, EH, H);
    }
}